// Round 1
// baseline (522.694 us; speedup 1.0000x reference)
//
#include <hip/hip_runtime.h>

#define NSEQ 512
#define RTOT (NSEQ*NSEQ)   // 262144 rows
#define DM 128

typedef unsigned short ushort_t;
using short8 = __attribute__((ext_vector_type(8))) short;
using f32x4  = __attribute__((ext_vector_type(4))) float;

__device__ __forceinline__ unsigned short f2bf(float x){
  union { float f; unsigned int u; } v; v.f = x;
  unsigned int r = v.u + 0x7fffu + ((v.u >> 16) & 1u);   // RNE
  return (unsigned short)(r >> 16);
}
__device__ __forceinline__ float bf2f(unsigned short u){
  union { unsigned int u; float f; } v; v.u = ((unsigned int)u) << 16;
  return v.f;
}
__device__ __forceinline__ unsigned int pack2(float a, float b){
  return (unsigned int)f2bf(a) | ((unsigned int)f2bf(b) << 16);
}
__device__ __forceinline__ float sigmoidf(float x){ return 1.0f/(1.0f + __expf(-x)); }

// ---------------- K0: LayerNorm(pair) -> lnx bf16 [R][128] -----------------
__global__ __launch_bounds__(256) void k0_ln_in(const float* __restrict__ pair,
                                                const float* __restrict__ w,
                                                const float* __restrict__ b,
                                                ushort_t* __restrict__ lnx){
  int wv = threadIdx.x >> 6, lane = threadIdx.x & 63;
  size_t row = (size_t)blockIdx.x * 4 + wv;          // one wave per row
  const float2* src = (const float2*)(pair + row * DM);
  float2 v = src[lane];
  float s = v.x + v.y, s2 = v.x*v.x + v.y*v.y;
  #pragma unroll
  for (int off = 32; off; off >>= 1){ s += __shfl_xor(s, off); s2 += __shfl_xor(s2, off); }
  float mu = s * (1.f/DM);
  float rstd = rsqrtf(s2*(1.f/DM) - mu*mu + 1e-5f);
  float o0 = (v.x - mu)*rstd*w[2*lane]   + b[2*lane];
  float o1 = (v.y - mu)*rstd*w[2*lane+1] + b[2*lane+1];
  ((unsigned int*)(lnx + row * DM))[lane] = pack2(o0, o1);
}

// ------ K1: Y = lnx · W^T, paired p/g cols; left/right = sig(g)*p ----------
// job 0: left d[0:64)   (p rows 0:64,   g rows 0:64)
// job 1: left d[64:128) (p rows 64:128, g rows 64:128)
// job 2: right d[0:64)  (rows 128:192); job 3: right d[64:128) (rows 192:256)
// Output layout: d-major [128][RTOT] bf16.
__global__ __launch_bounds__(256) void k1_inproj(const ushort_t* __restrict__ lnx,
                                                 const float* __restrict__ p_in_w,
                                                 const float* __restrict__ g_in_w,
                                                 ushort_t* __restrict__ left,
                                                 ushort_t* __restrict__ right){
  __shared__ __align__(16) ushort_t A[64][136];    // 64 rows x 128 k (pad->136)
  __shared__ __align__(16) ushort_t B[128][136];   // 64 p-rows + 64 g-rows
  int tid = threadIdx.x;
  int job = blockIdx.x;                 // 0..3
  int bm  = blockIdx.y;                 // 0..4095
  int wrow0 = ((job >= 2) ? 128 : 0) + (job & 1) * 64;
  ushort_t* outp = (job >= 2) ? right : left;
  int dbase = (job & 1) * 64;
  size_t arow0 = (size_t)bm * 64;

  #pragma unroll
  for (int it = 0; it < 4; it++){                  // stage A (bf16 16B loads)
    int e = (tid + it*256) * 8; int r = e >> 7, c = e & 127;
    *(uint4*)&A[r][c] = *(const uint4*)&lnx[(arow0 + r)*DM + c];
  }
  #pragma unroll
  for (int it = 0; it < 16; it++){                 // stage B (fp32 -> bf16)
    int e = (tid + it*256) * 4; int r = e >> 7, c = e & 127;
    const float* srcw = (r < 64) ? (p_in_w + (size_t)(wrow0 + r)*DM + c)
                                 : (g_in_w + (size_t)(wrow0 + r - 64)*DM + c);
    float4 wv = *(const float4*)srcw;
    uint2 pk; pk.x = pack2(wv.x, wv.y); pk.y = pack2(wv.z, wv.w);
    *(uint2*)&B[r][c] = pk;
  }
  __syncthreads();

  int w = tid >> 6, lane = tid & 63, m = lane & 15, quad = lane >> 4;
  f32x4 acc[8];
  #pragma unroll
  for (int i = 0; i < 8; i++) acc[i] = (f32x4){0.f,0.f,0.f,0.f};
  #pragma unroll
  for (int k0 = 0; k0 < 128; k0 += 32){
    short8 a = *(const short8*)&A[w*16 + m][k0 + quad*8];
    #pragma unroll
    for (int c = 0; c < 8; c++){
      short8 bf = *(const short8*)&B[c*16 + m][k0 + quad*8];
      acc[c] = __builtin_amdgcn_mfma_f32_16x16x32_bf16(a, bf, acc[c], 0, 0, 0);
    }
  }
  // epilogue: tiles c (p) pair with c+4 (g); rows quad*4+rr are contiguous -> ushort4
  size_t r0 = arow0 + w*16 + quad*4;
  #pragma unroll
  for (int c = 0; c < 4; c++){
    int d = dbase + c*16 + m;
    uint2 pk;
    pk.x = pack2(sigmoidf(acc[c+4][0]) * acc[c][0], sigmoidf(acc[c+4][1]) * acc[c][1]);
    pk.y = pack2(sigmoidf(acc[c+4][2]) * acc[c][2], sigmoidf(acc[c+4][3]) * acc[c][3]);
    *(uint2*)&outp[(size_t)d * RTOT + r0] = pk;
  }
}

// ------- K2: per d-plane NT GEMM: tri[d][i][j] = sum_k L[i,k]R[j,k]/L ------
__global__ __launch_bounds__(256) void k2_tri(const ushort_t* __restrict__ left,
                                              const ushort_t* __restrict__ right,
                                              ushort_t* __restrict__ tri){
  __shared__ __align__(16) ushort_t As[64][72];
  __shared__ __align__(16) ushort_t Bs[64][72];
  int tid = threadIdx.x;
  int jb = blockIdx.x, ib = blockIdx.y, d = blockIdx.z;
  const ushort_t* Ap = left  + (size_t)d * RTOT;
  const ushort_t* Bp = right + (size_t)d * RTOT;
  int i0 = ib*64, j0 = jb*64;
  int w = tid >> 6, lane = tid & 63, m = lane & 15, quad = lane >> 4;
  f32x4 acc[4];
  #pragma unroll
  for (int i = 0; i < 4; i++) acc[i] = (f32x4){0.f,0.f,0.f,0.f};

  for (int kt = 0; kt < NSEQ; kt += 64){
    __syncthreads();
    #pragma unroll
    for (int it = 0; it < 2; it++){
      int e = (tid + it*256) * 8; int r = e >> 6, c = e & 63;
      *(uint4*)&As[r][c] = *(const uint4*)&Ap[(size_t)(i0 + r)*NSEQ + kt + c];
      *(uint4*)&Bs[r][c] = *(const uint4*)&Bp[(size_t)(j0 + r)*NSEQ + kt + c];
    }
    __syncthreads();
    #pragma unroll
    for (int kk = 0; kk < 64; kk += 32){
      short8 a = *(const short8*)&As[w*16 + m][kk + quad*8];
      #pragma unroll
      for (int c = 0; c < 4; c++){
        short8 bf = *(const short8*)&Bs[c*16 + m][kk + quad*8];
        acc[c] = __builtin_amdgcn_mfma_f32_16x16x32_bf16(a, bf, acc[c], 0, 0, 0);
      }
    }
  }
  const float scale = 1.f / (float)NSEQ;
  ushort_t* outp = tri + (size_t)d * RTOT;
  #pragma unroll
  for (int c = 0; c < 4; c++){
    #pragma unroll
    for (int rr = 0; rr < 4; rr++){
      int row = i0 + w*16 + quad*4 + rr;
      int col = j0 + c*16 + m;
      outp[(size_t)row * NSEQ + col] = f2bf(acc[c][rr] * scale);
    }
  }
}

// --- K3: LN(tri) -> out-proj; lnx -> gate-proj; out = sig(gate)*proj ------
__global__ __launch_bounds__(256) void k3_out(const ushort_t* __restrict__ tri,
                                              const ushort_t* __restrict__ lnx,
                                              const float* __restrict__ lnw,
                                              const float* __restrict__ lnb,
                                              const float* __restrict__ p_out_w,
                                              const float* __restrict__ g_out_w,
                                              float* __restrict__ out){
  __shared__ __align__(16) ushort_t A1[64][136];   // LN(tri) rows
  __shared__ __align__(16) ushort_t A2[64][136];   // lnx rows
  __shared__ __align__(16) ushort_t Bt[64][136];   // weight chunk (64 rows)
  int tid = threadIdx.x;
  size_t r0 = (size_t)blockIdx.x * 64;

  #pragma unroll
  for (int it = 0; it < 4; it++){                  // stage A2 = lnx
    int e = (tid + it*256) * 8; int r = e >> 7, c = e & 127;
    *(uint4*)&A2[r][c] = *(const uint4*)&lnx[(r0 + r)*DM + c];
  }
  {                                                // stage A1 = tri^T (d-major -> row-major)
    int dch = tid >> 1, half = tid & 1;
    const ushort_t* src = tri + (size_t)dch * RTOT + r0 + half*32;
    #pragma unroll
    for (int q = 0; q < 4; q++){
      uint4 v = *(const uint4*)(src + q*8);
      int rb = half*32 + q*8;
      A1[rb+0][dch] = (ushort_t)(v.x & 0xffff); A1[rb+1][dch] = (ushort_t)(v.x >> 16);
      A1[rb+2][dch] = (ushort_t)(v.y & 0xffff); A1[rb+3][dch] = (ushort_t)(v.y >> 16);
      A1[rb+4][dch] = (ushort_t)(v.z & 0xffff); A1[rb+5][dch] = (ushort_t)(v.z >> 16);
      A1[rb+6][dch] = (ushort_t)(v.w & 0xffff); A1[rb+7][dch] = (ushort_t)(v.w >> 16);
    }
  }
  __syncthreads();
  {                                                // in-place LN of A1 rows (4 lanes/row)
    int row = tid >> 2, part = tid & 3;
    float x[32]; float s = 0.f, s2 = 0.f;
    #pragma unroll
    for (int j = 0; j < 32; j++){ x[j] = bf2f(A1[row][part*32 + j]); s += x[j]; s2 += x[j]*x[j]; }
    s += __shfl_xor(s, 1); s2 += __shfl_xor(s2, 1);
    s += __shfl_xor(s, 2); s2 += __shfl_xor(s2, 2);
    float mu = s * (1.f/DM);
    float rstd = rsqrtf(s2*(1.f/DM) - mu*mu + 1e-5f);
    #pragma unroll
    for (int j = 0; j < 32; j++){
      int cc = part*32 + j;
      A1[row][cc] = f2bf((x[j] - mu)*rstd*lnw[cc] + lnb[cc]);
    }
  }
  __syncthreads();

  int w = tid >> 6, lane = tid & 63, m = lane & 15, quad = lane >> 4;
  #pragma unroll
  for (int ch = 0; ch < 2; ch++){                  // 64 output cols per chunk
    f32x4 accp[4], accg[4];
    #pragma unroll
    for (int i = 0; i < 4; i++){ accp[i] = (f32x4){0.f,0.f,0.f,0.f}; accg[i] = (f32x4){0.f,0.f,0.f,0.f}; }

    #pragma unroll
    for (int it = 0; it < 8; it++){                // Bt <- p_out_w rows
      int e = (tid + it*256) * 4; int r = e >> 7, c = e & 127;
      float4 wv = *(const float4*)&p_out_w[(size_t)(ch*64 + r)*DM + c];
      uint2 pk; pk.x = pack2(wv.x, wv.y); pk.y = pack2(wv.z, wv.w);
      *(uint2*)&Bt[r][c] = pk;
    }
    __syncthreads();
    #pragma unroll
    for (int k0 = 0; k0 < 128; k0 += 32){
      short8 a = *(const short8*)&A1[w*16 + m][k0 + quad*8];
      #pragma unroll
      for (int c = 0; c < 4; c++){
        short8 bf = *(const short8*)&Bt[c*16 + m][k0 + quad*8];
        accp[c] = __builtin_amdgcn_mfma_f32_16x16x32_bf16(a, bf, accp[c], 0, 0, 0);
      }
    }
    __syncthreads();
    #pragma unroll
    for (int it = 0; it < 8; it++){                // Bt <- g_out_w rows
      int e = (tid + it*256) * 4; int r = e >> 7, c = e & 127;
      float4 wv = *(const float4*)&g_out_w[(size_t)(ch*64 + r)*DM + c];
      uint2 pk; pk.x = pack2(wv.x, wv.y); pk.y = pack2(wv.z, wv.w);
      *(uint2*)&Bt[r][c] = pk;
    }
    __syncthreads();
    #pragma unroll
    for (int k0 = 0; k0 < 128; k0 += 32){
      short8 a = *(const short8*)&A2[w*16 + m][k0 + quad*8];
      #pragma unroll
      for (int c = 0; c < 4; c++){
        short8 bf = *(const short8*)&Bt[c*16 + m][k0 + quad*8];
        accg[c] = __builtin_amdgcn_mfma_f32_16x16x32_bf16(a, bf, accg[c], 0, 0, 0);
      }
    }
    #pragma unroll
    for (int c = 0; c < 4; c++){
      int dcol = ch*64 + c*16 + m;
      #pragma unroll
      for (int rr = 0; rr < 4; rr++){
        size_t row = r0 + w*16 + quad*4 + rr;
        out[row * DM + dcol] = sigmoidf(accg[c][rr]) * accp[c][rr];
      }
    }
    __syncthreads();                               // protect Bt for next chunk
  }
}

extern "C" void kernel_launch(void* const* d_in, const int* in_sizes, int n_in,
                              void* d_out, int out_size, void* d_ws, size_t ws_size,
                              hipStream_t stream){
  const float* pair     = (const float*)d_in[0];
  const float* ln_in_w  = (const float*)d_in[1];
  const float* ln_in_b  = (const float*)d_in[2];
  const float* p_in_w   = (const float*)d_in[3];
  const float* g_in_w   = (const float*)d_in[4];
  const float* ln_out_w = (const float*)d_in[5];
  const float* ln_out_b = (const float*)d_in[6];
  const float* p_out_w  = (const float*)d_in[7];
  const float* g_out_w  = (const float*)d_in[8];
  float* out = (float*)d_out;

  const size_t plane = (size_t)RTOT * DM;          // 33.5M elems, 64 MB bf16
  ushort_t* lnx   = (ushort_t*)d_ws;
  ushort_t* left  = lnx   + plane;
  ushort_t* right = left  + plane;
  ushort_t* tri   = right + plane;                 // total 256 MB

  k0_ln_in <<<dim3(RTOT/4),      dim3(256), 0, stream>>>(pair, ln_in_w, ln_in_b, lnx);
  k1_inproj<<<dim3(4, RTOT/64),  dim3(256), 0, stream>>>(lnx, p_in_w, g_in_w, left, right);
  k2_tri   <<<dim3(8, 8, 128),   dim3(256), 0, stream>>>(left, right, tri);
  k3_out   <<<dim3(RTOT/64),     dim3(256), 0, stream>>>(tri, lnx, ln_out_w, ln_out_b,
                                                         p_out_w, g_out_w, out);
}

// Round 2
// 462.355 us; speedup vs baseline: 1.1305x; 1.1305x over previous
//
#include <hip/hip_runtime.h>

#define NSEQ 512
#define RTOT (NSEQ*NSEQ)   // 262144 rows
#define DM 128

typedef unsigned short ushort_t;
using short8 = __attribute__((ext_vector_type(8))) short;
using f32x4  = __attribute__((ext_vector_type(4))) float;

__device__ __forceinline__ unsigned short f2bf(float x){
  union { float f; unsigned int u; } v; v.f = x;
  unsigned int r = v.u + 0x7fffu + ((v.u >> 16) & 1u);   // RNE
  return (unsigned short)(r >> 16);
}
__device__ __forceinline__ float bf2f(unsigned short u){
  union { unsigned int u; float f; } v; v.u = ((unsigned int)u) << 16;
  return v.f;
}
__device__ __forceinline__ unsigned int pack2(float a, float b){
  return (unsigned int)f2bf(a) | ((unsigned int)f2bf(b) << 16);
}
__device__ __forceinline__ float sigmoidf(float x){ return 1.0f/(1.0f + __expf(-x)); }

// -------- K_prep: one-shot fp32 -> bf16 weight conversion ------------------
__global__ __launch_bounds__(256) void k_prep(const float* __restrict__ a,
                                              const float* __restrict__ b,
                                              ushort_t* __restrict__ da,
                                              ushort_t* __restrict__ db,
                                              int na4, int nb4){
  int idx = blockIdx.x*256 + threadIdx.x;
  const float* src; ushort_t* dst; int i;
  if (idx < na4){ src = a; dst = da; i = idx; }
  else { i = idx - na4; if (i >= nb4) return; src = b; dst = db; }
  float4 v = *(const float4*)(src + (size_t)i*4);
  uint2 pk; pk.x = pack2(v.x, v.y); pk.y = pack2(v.z, v.w);
  *(uint2*)(dst + (size_t)i*4) = pk;
}

// ---------------- K0: LayerNorm(pair) -> lnx bf16 [R][128] -----------------
__global__ __launch_bounds__(256) void k0_ln_in(const float* __restrict__ pair,
                                                const float* __restrict__ w,
                                                const float* __restrict__ b,
                                                ushort_t* __restrict__ lnx){
  int wv = threadIdx.x >> 6, lane = threadIdx.x & 63;
  size_t row = (size_t)blockIdx.x * 4 + wv;          // one wave per row
  const float2* src = (const float2*)(pair + row * DM);
  float2 v = src[lane];
  float s = v.x + v.y, s2 = v.x*v.x + v.y*v.y;
  #pragma unroll
  for (int off = 32; off; off >>= 1){ s += __shfl_xor(s, off); s2 += __shfl_xor(s2, off); }
  float mu = s * (1.f/DM);
  float rstd = rsqrtf(s2*(1.f/DM) - mu*mu + 1e-5f);
  float o0 = (v.x - mu)*rstd*w[2*lane]   + b[2*lane];
  float o1 = (v.y - mu)*rstd*w[2*lane+1] + b[2*lane+1];
  ((unsigned int*)(lnx + row * DM))[lane] = pack2(o0, o1);
}

// ------ K1: Y = lnx · W^T, paired p/g cols; left/right = sig(g)*p ----------
// Weights pre-converted to bf16 (pw_bf/gw_bf). Output d-major [128][RTOT].
__global__ __launch_bounds__(256) void k1_inproj(const ushort_t* __restrict__ lnx,
                                                 const ushort_t* __restrict__ pw_bf,
                                                 const ushort_t* __restrict__ gw_bf,
                                                 ushort_t* __restrict__ left,
                                                 ushort_t* __restrict__ right){
  __shared__ __align__(16) ushort_t A[64][136];    // 64 rows x 128 k (pad->136)
  __shared__ __align__(16) ushort_t B[128][136];   // 64 p-rows + 64 g-rows
  int tid = threadIdx.x;
  int job = blockIdx.x;                 // 0..3
  int bm  = blockIdx.y;                 // 0..4095
  int wrow0 = ((job >= 2) ? 128 : 0) + (job & 1) * 64;
  ushort_t* outp = (job >= 2) ? right : left;
  int dbase = (job & 1) * 64;
  size_t arow0 = (size_t)bm * 64;

  #pragma unroll
  for (int it = 0; it < 4; it++){                  // stage A (bf16 16B loads)
    int e = (tid + it*256) * 8; int r = e >> 7, c = e & 127;
    *(uint4*)&A[r][c] = *(const uint4*)&lnx[(arow0 + r)*DM + c];
  }
  #pragma unroll
  for (int it = 0; it < 8; it++){                  // stage B (bf16 copy)
    int e = (tid + it*256) * 8; int r = e >> 7, c = e & 127;
    const ushort_t* srcw = (r < 64) ? &pw_bf[(size_t)(wrow0 + r)*DM + c]
                                    : &gw_bf[(size_t)(wrow0 + r - 64)*DM + c];
    *(uint4*)&B[r][c] = *(const uint4*)srcw;
  }
  __syncthreads();

  int w = tid >> 6, lane = tid & 63, m = lane & 15, quad = lane >> 4;
  f32x4 acc[8];
  #pragma unroll
  for (int i = 0; i < 8; i++) acc[i] = (f32x4){0.f,0.f,0.f,0.f};
  #pragma unroll
  for (int k0 = 0; k0 < 128; k0 += 32){
    short8 a = *(const short8*)&A[w*16 + m][k0 + quad*8];
    #pragma unroll
    for (int c = 0; c < 8; c++){
      short8 bf = *(const short8*)&B[c*16 + m][k0 + quad*8];
      acc[c] = __builtin_amdgcn_mfma_f32_16x16x32_bf16(a, bf, acc[c], 0, 0, 0);
    }
  }
  size_t r0 = arow0 + w*16 + quad*4;
  #pragma unroll
  for (int c = 0; c < 4; c++){
    int d = dbase + c*16 + m;
    uint2 pk;
    pk.x = pack2(sigmoidf(acc[c+4][0]) * acc[c][0], sigmoidf(acc[c+4][1]) * acc[c][1]);
    pk.y = pack2(sigmoidf(acc[c+4][2]) * acc[c][2], sigmoidf(acc[c+4][3]) * acc[c][3]);
    *(uint2*)&outp[(size_t)d * RTOT + r0] = pk;
  }
}

// ------- K2: per d-plane NT GEMM: tri[d][i][j] = sum_k L[i,k]R[j,k]/L ------
// 128x512 per block (d, ti), 4 internal j-chunks of 128. XCD swizzle:
// b = ti*128 + d keeps each d-plane on one XCD (b%8 == d%8).
__global__ __launch_bounds__(256) void k2_tri(const ushort_t* __restrict__ left,
                                              const ushort_t* __restrict__ right,
                                              ushort_t* __restrict__ tri){
  __shared__ __align__(16) ushort_t As[128][72];
  __shared__ __align__(16) ushort_t Bs[128][72];
  int tid = threadIdx.x;
  int b = blockIdx.x;
  int d = b & 127, ti = b >> 7;
  const ushort_t* Ap = left  + (size_t)d * RTOT;
  const ushort_t* Bp = right + (size_t)d * RTOT;
  ushort_t* Cp = tri + (size_t)d * RTOT;
  int i0 = ti * 128;
  int w = tid >> 6, lane = tid & 63, m = lane & 15, quad = lane >> 4;
  int wr = w & 1, wc = w >> 1;

  for (int tj = 0; tj < 4; tj++){
    int j0 = tj * 128;
    f32x4 acc[16];
    #pragma unroll
    for (int x = 0; x < 16; x++) acc[x] = (f32x4){0.f,0.f,0.f,0.f};

    for (int kt = 0; kt < NSEQ; kt += 64){
      __syncthreads();
      #pragma unroll
      for (int it = 0; it < 4; it++){
        int e = (tid + it*256) * 8; int r = e >> 6, c = e & 63;
        *(uint4*)&As[r][c] = *(const uint4*)&Ap[(size_t)(i0 + r)*NSEQ + kt + c];
        *(uint4*)&Bs[r][c] = *(const uint4*)&Bp[(size_t)(j0 + r)*NSEQ + kt + c];
      }
      __syncthreads();
      #pragma unroll
      for (int kk = 0; kk < 64; kk += 32){
        short8 a[4], bb[4];
        #pragma unroll
        for (int t = 0; t < 4; t++) a[t]  = *(const short8*)&As[wr*64 + t*16 + m][kk + quad*8];
        #pragma unroll
        for (int c = 0; c < 4; c++) bb[c] = *(const short8*)&Bs[wc*64 + c*16 + m][kk + quad*8];
        #pragma unroll
        for (int t = 0; t < 4; t++){
          #pragma unroll
          for (int c = 0; c < 4; c++){
            acc[t*4+c] = __builtin_amdgcn_mfma_f32_16x16x32_bf16(a[t], bb[c], acc[t*4+c], 0, 0, 0);
          }
        }
      }
    }
    const float s = 1.f / (float)NSEQ;
    #pragma unroll
    for (int t = 0; t < 4; t++){
      #pragma unroll
      for (int c = 0; c < 4; c++){
        int col = j0 + wc*64 + c*16 + m;
        #pragma unroll
        for (int rr = 0; rr < 4; rr++){
          int row = i0 + wr*64 + t*16 + quad*4 + rr;
          Cp[(size_t)row * NSEQ + col] = f2bf(acc[t*4+c][rr] * s);
        }
      }
    }
  }
}

// --- K3: LN(tri) -> out-proj; lnx -> gate-proj; out = sig(gate)*proj ------
__global__ __launch_bounds__(256) void k3_out(const ushort_t* __restrict__ tri,
                                              const ushort_t* __restrict__ lnx,
                                              const float* __restrict__ lnw,
                                              const float* __restrict__ lnb,
                                              const ushort_t* __restrict__ pow_bf,
                                              const ushort_t* __restrict__ gow_bf,
                                              float* __restrict__ out){
  __shared__ __align__(16) ushort_t A1[64][136];   // LN(tri) rows
  __shared__ __align__(16) ushort_t A2[64][136];   // lnx rows
  __shared__ __align__(16) ushort_t Bt[64][136];   // weight chunk (64 rows)
  __shared__ float lw[128], lb[128];
  int tid = threadIdx.x;
  size_t r0 = (size_t)blockIdx.x * 64;

  if (tid < 128){ lw[tid] = lnw[tid]; lb[tid] = lnb[tid]; }
  #pragma unroll
  for (int it = 0; it < 4; it++){                  // stage A2 = lnx
    int e = (tid + it*256) * 8; int r = e >> 7, c = e & 127;
    *(uint4*)&A2[r][c] = *(const uint4*)&lnx[(r0 + r)*DM + c];
  }
  {                                                // stage A1 = tri^T (d-major -> row-major)
    int dch = tid >> 1, half = tid & 1;
    const ushort_t* src = tri + (size_t)dch * RTOT + r0 + half*32;
    #pragma unroll
    for (int q = 0; q < 4; q++){
      uint4 v = *(const uint4*)(src + q*8);
      int rb = half*32 + q*8;
      A1[rb+0][dch] = (ushort_t)(v.x & 0xffff); A1[rb+1][dch] = (ushort_t)(v.x >> 16);
      A1[rb+2][dch] = (ushort_t)(v.y & 0xffff); A1[rb+3][dch] = (ushort_t)(v.y >> 16);
      A1[rb+4][dch] = (ushort_t)(v.z & 0xffff); A1[rb+5][dch] = (ushort_t)(v.z >> 16);
      A1[rb+6][dch] = (ushort_t)(v.w & 0xffff); A1[rb+7][dch] = (ushort_t)(v.w >> 16);
    }
  }
  __syncthreads();
  {                                                // in-place LN of A1 rows (4 lanes/row)
    int row = tid >> 2, part = tid & 3;
    float x[32]; float s = 0.f, s2 = 0.f;
    #pragma unroll
    for (int j = 0; j < 32; j++){ x[j] = bf2f(A1[row][part*32 + j]); s += x[j]; s2 += x[j]*x[j]; }
    s += __shfl_xor(s, 1); s2 += __shfl_xor(s2, 1);
    s += __shfl_xor(s, 2); s2 += __shfl_xor(s2, 2);
    float mu = s * (1.f/DM);
    float rstd = rsqrtf(s2*(1.f/DM) - mu*mu + 1e-5f);
    #pragma unroll
    for (int j = 0; j < 32; j++){
      int cc = part*32 + j;
      A1[row][cc] = f2bf((x[j] - mu)*rstd*lw[cc] + lb[cc]);
    }
  }
  __syncthreads();

  int w = tid >> 6, lane = tid & 63, m = lane & 15, quad = lane >> 4;
  #pragma unroll
  for (int ch = 0; ch < 2; ch++){                  // 64 output cols per chunk
    f32x4 accp[4], accg[4];
    #pragma unroll
    for (int i = 0; i < 4; i++){ accp[i] = (f32x4){0.f,0.f,0.f,0.f}; accg[i] = (f32x4){0.f,0.f,0.f,0.f}; }

    #pragma unroll
    for (int it = 0; it < 4; it++){                // Bt <- p_out_w rows (bf16 copy)
      int e = (tid + it*256) * 8; int r = e >> 7, c = e & 127;
      *(uint4*)&Bt[r][c] = *(const uint4*)&pow_bf[(size_t)(ch*64 + r)*DM + c];
    }
    __syncthreads();
    #pragma unroll
    for (int k0 = 0; k0 < 128; k0 += 32){
      short8 a = *(const short8*)&A1[w*16 + m][k0 + quad*8];
      #pragma unroll
      for (int c = 0; c < 4; c++){
        short8 bf = *(const short8*)&Bt[c*16 + m][k0 + quad*8];
        accp[c] = __builtin_amdgcn_mfma_f32_16x16x32_bf16(a, bf, accp[c], 0, 0, 0);
      }
    }
    __syncthreads();
    #pragma unroll
    for (int it = 0; it < 4; it++){                // Bt <- g_out_w rows (bf16 copy)
      int e = (tid + it*256) * 8; int r = e >> 7, c = e & 127;
      *(uint4*)&Bt[r][c] = *(const uint4*)&gow_bf[(size_t)(ch*64 + r)*DM + c];
    }
    __syncthreads();
    #pragma unroll
    for (int k0 = 0; k0 < 128; k0 += 32){
      short8 a = *(const short8*)&A2[w*16 + m][k0 + quad*8];
      #pragma unroll
      for (int c = 0; c < 4; c++){
        short8 bf = *(const short8*)&Bt[c*16 + m][k0 + quad*8];
        accg[c] = __builtin_amdgcn_mfma_f32_16x16x32_bf16(a, bf, accg[c], 0, 0, 0);
      }
    }
    #pragma unroll
    for (int c = 0; c < 4; c++){
      int dcol = ch*64 + c*16 + m;
      #pragma unroll
      for (int rr = 0; rr < 4; rr++){
        size_t row = r0 + w*16 + quad*4 + rr;
        out[row * DM + dcol] = sigmoidf(accg[c][rr]) * accp[c][rr];
      }
    }
    __syncthreads();                               // protect Bt for next chunk
  }
}

extern "C" void kernel_launch(void* const* d_in, const int* in_sizes, int n_in,
                              void* d_out, int out_size, void* d_ws, size_t ws_size,
                              hipStream_t stream){
  const float* pair     = (const float*)d_in[0];
  const float* ln_in_w  = (const float*)d_in[1];
  const float* ln_in_b  = (const float*)d_in[2];
  const float* p_in_w   = (const float*)d_in[3];
  const float* g_in_w   = (const float*)d_in[4];
  const float* ln_out_w = (const float*)d_in[5];
  const float* ln_out_b = (const float*)d_in[6];
  const float* p_out_w  = (const float*)d_in[7];
  const float* g_out_w  = (const float*)d_in[8];
  float* out = (float*)d_out;

  const size_t plane = (size_t)RTOT * DM;          // 33.5M elems, 64 MB bf16
  ushort_t* lnx   = (ushort_t*)d_ws;
  ushort_t* left  = lnx   + plane;
  ushort_t* right = left  + plane;
  ushort_t* tri   = right + plane;                 // total 256 MB

  // bf16 weight overlays in dead regions:
  //  - pw/gw (k1) live in tri's head: written pre-k0, read by k1, clobbered by k2.
  //  - pow/gow (k3) live in left's head: written AFTER k2 (left dead), read by k3.
  ushort_t* pw_bf  = tri;            // 256*128
  ushort_t* gw_bf  = tri + 32768;    // 256*128
  ushort_t* pow_bf = left;           // 128*128
  ushort_t* gow_bf = left + 16384;   // 128*128

  k_prep   <<<dim3(64),          dim3(256), 0, stream>>>(p_in_w, g_in_w, pw_bf, gw_bf, 8192, 8192);
  k0_ln_in <<<dim3(RTOT/4),      dim3(256), 0, stream>>>(pair, ln_in_w, ln_in_b, lnx);
  k1_inproj<<<dim3(4, RTOT/64),  dim3(256), 0, stream>>>(lnx, pw_bf, gw_bf, left, right);
  k2_tri   <<<dim3(512),         dim3(256), 0, stream>>>(left, right, tri);
  k_prep   <<<dim3(32),          dim3(256), 0, stream>>>(p_out_w, g_out_w, pow_bf, gow_bf, 4096, 4096);
  k3_out   <<<dim3(RTOT/64),     dim3(256), 0, stream>>>(tri, lnx, ln_out_w, ln_out_b,
                                                         pow_bf, gow_bf, out);
}